// Round 1
// baseline (244.727 us; speedup 1.0000x reference)
//
#include <hip/hip_runtime.h>
#include <cstdint>

// ---------------------------------------------------------------------------
// DefaultAttention: x[4,2048,1024] fp32; k=xWk^T+bk, q=xWq^T+bq, v=xWv^T+bv;
// sim = k q^T / 32 (causal tril), attn = softmax(sim), out = attn @ v (fp32).
// R12: qkv moved to a 256x256 / BK=64 / 8-wave / 8-phase counted-vmcnt
// pipeline (T2 swizzle + T3/T4 counted vmcnt + T5 setprio). The old 2-barrier
// BK=32 structure drained vmcnt(0) every K-step (MfmaUtil 30%); the 8-phase
// schedule keeps 2-3 half-tiles in flight across barriers (vmcnt(4)).
// Schedule verified on paper: stage slots {p0:cur1.A1, p1:cur1.B1,
// p2..p5: T+2 A0,B0,A1,B1, p6,p7: T+3 A0,B0}; every overwritten LDS half is
// dead >=1 phase before its stage issues (WAR), every consumed tile is fully
// landed at the preceding vmcnt(4)+barrier (RAW).
// scores/pv keep the R11 BK=64 dbuf structure (unchanged this round).
// ---------------------------------------------------------------------------

typedef __attribute__((ext_vector_type(8))) _Float16 f16x8;
typedef __attribute__((ext_vector_type(4))) float f32x4;

__device__ __forceinline__ unsigned short f2h(float x) {
  return __builtin_bit_cast(unsigned short, (_Float16)x);
}

// async global->LDS, 16B per lane; LDS dest = wave-uniform base + lane*16
__device__ __forceinline__ void lds_dma16(const void* g, void* l) {
  auto gp = reinterpret_cast<const __attribute__((address_space(1))) void*>(
      reinterpret_cast<uintptr_t>(g));
  auto lp = reinterpret_cast<__attribute__((address_space(3))) void*>(
      reinterpret_cast<uintptr_t>(l));
  __builtin_amdgcn_global_load_lds(gp, lp, 16, 0, 0);
}

// ---------------------------------------------------------------------------
// 256x256 8-phase pieces.
// Half-tile = 128 rows x 64 cols f16 (16 KB). Linear LDS dest (DMA rule);
// swizzle via pre-swizzled global source: LDS slot s of row r holds source
// col-block s^(r&7); readers use slot (cb ^ (r&7)).  [R3-verified scheme]
// ---------------------------------------------------------------------------
__device__ __forceinline__ void stage_half(const unsigned short* __restrict__ G,
                                           int ld, unsigned short* lds,
                                           int tid) {
  const int r = tid >> 3;                      // rows 0..63 (issue 0)
  const int c = ((tid & 7) ^ (r & 7)) * 8;     // swizzled source col (ush)
  lds_dma16(G + (size_t)r * ld + c, lds + tid * 8);
  lds_dma16(G + (size_t)(r + 64) * ld + c, lds + 4096 + tid * 8);  // rows 64..127
}

// One iteration = 2 K-tiles (k0, k0+64) = 8 phases. Phase p: buf=p>>2,
// C-quadrant (qm,qn)=((p>>1)&1, p&1). 16 MFMA + 12 ds_read_b128 per wave
// per phase; one half-tile staged per phase; vmcnt(4) at p3/p7 only.
__device__ __forceinline__ void g256_iter(
    const unsigned short* __restrict__ Ag, const unsigned short* __restrict__ Bg,
    int lda, int ldb, unsigned short* As, unsigned short* Bs,
    f32x4 (&acc)[2][2][2][4], int k0, bool last) {
  const int tid = threadIdx.x;
  const int lane = tid & 63, wave = tid >> 6;
  const int qwm = wave >> 1, qwn = wave & 1;   // 4x2 wave grid in a quadrant
  const int rr = lane & 15, qq = lane >> 4;
  const int arow = (qwm * 32 + rr) * 64;
  const int brow = (qwn * 64 + rr) * 64;
  const int s7 = rr & 7;
  const int soff0 = (qq ^ s7) * 8;             // k-half 0 swizzled slot
  const int soff1 = ((4 + qq) ^ s7) * 8;       // k-half 1

#pragma unroll
  for (int p = 0; p < 8; ++p) {
    const int buf = p >> 2, qm = (p >> 1) & 1, qn = p & 1;
    const unsigned short* Ar = As + buf * 16384 + qm * 8192 + arow;
    const unsigned short* Br = Bs + buf * 16384 + qn * 8192 + brow;
    f16x8 af[2][2], bf[4][2];
#pragma unroll
    for (int fi = 0; fi < 2; ++fi) {
      af[fi][0] = *(const f16x8*)(Ar + fi * 1024 + soff0);
      af[fi][1] = *(const f16x8*)(Ar + fi * 1024 + soff1);
    }
#pragma unroll
    for (int fj = 0; fj < 4; ++fj) {
      bf[fj][0] = *(const f16x8*)(Br + fj * 1024 + soff0);
      bf[fj][1] = *(const f16x8*)(Br + fj * 1024 + soff1);
    }

    // staging schedule (see header comment); cur1 tail halves always staged
    if (p == 0) {
      stage_half(Ag + (size_t)128 * lda + (k0 + 64), lda, As + 24576, tid);
    } else if (p == 1) {
      stage_half(Bg + (size_t)128 * ldb + (k0 + 64), ldb, Bs + 24576, tid);
    } else if (!last) {
      if (p == 2)      stage_half(Ag + (k0 + 128), lda, As, tid);
      else if (p == 3) stage_half(Bg + (k0 + 128), ldb, Bs, tid);
      else if (p == 4) stage_half(Ag + (size_t)128 * lda + (k0 + 128), lda, As + 8192, tid);
      else if (p == 5) stage_half(Bg + (size_t)128 * ldb + (k0 + 128), ldb, Bs + 8192, tid);
      else if (p == 6) stage_half(Ag + (k0 + 192), lda, As + 16384, tid);
      else             stage_half(Bg + (k0 + 192), ldb, Bs + 16384, tid);
    }

    asm volatile("s_waitcnt lgkmcnt(8)" ::: "memory");
    __builtin_amdgcn_s_barrier();
    asm volatile("s_waitcnt lgkmcnt(0)" ::: "memory");
    __builtin_amdgcn_sched_barrier(0);
    __builtin_amdgcn_s_setprio(1);
#pragma unroll
    for (int h = 0; h < 2; ++h)
#pragma unroll
      for (int fi = 0; fi < 2; ++fi)
#pragma unroll
        for (int fj = 0; fj < 4; ++fj)
          acc[qm][qn][fi][fj] = __builtin_amdgcn_mfma_f32_16x16x32_f16(
              af[fi][h], bf[fj][h], acc[qm][qn][fi][fj], 0, 0, 0);
    __builtin_amdgcn_s_setprio(0);
    if (p == 3) {
      if (last) asm volatile("s_waitcnt vmcnt(0)" ::: "memory");
      else      asm volatile("s_waitcnt vmcnt(4)" ::: "memory");
    } else if (p == 7 && !last) {
      asm volatile("s_waitcnt vmcnt(4)" ::: "memory");
    }
    __builtin_amdgcn_s_barrier();
  }
}

// C[256x256] = A[256 x nk] * B[256 x nk]^T, nk % 128 == 0, nk >= 128.
__device__ __forceinline__ void gemm256(
    const unsigned short* __restrict__ Ag, const unsigned short* __restrict__ Bg,
    int lda, int ldb, int nk, unsigned short* As, unsigned short* Bs,
    f32x4 (&acc)[2][2][2][4]) {
  const int tid = threadIdx.x;
#pragma unroll
  for (int a = 0; a < 2; ++a)
#pragma unroll
    for (int b = 0; b < 2; ++b)
#pragma unroll
      for (int c = 0; c < 2; ++c)
#pragma unroll
      for (int d = 0; d < 4; ++d) {
        f32x4 z = {0.f, 0.f, 0.f, 0.f};
        acc[a][b][c][d] = z;
      }

  // prologue: tile0 (all 4 halves) + tile1 {A0,B0}; vmcnt(4) -> tile0 landed
  stage_half(Ag, lda, As, tid);
  stage_half(Ag + (size_t)128 * lda, lda, As + 8192, tid);
  stage_half(Bg, ldb, Bs, tid);
  stage_half(Bg + (size_t)128 * ldb, ldb, Bs + 8192, tid);
  stage_half(Ag + 64, lda, As + 16384, tid);
  stage_half(Bg + 64, ldb, Bs + 16384, tid);
  asm volatile("s_waitcnt vmcnt(4)" ::: "memory");
  __builtin_amdgcn_s_barrier();

  const int NIT = nk >> 7;
  for (int it = 0; it < NIT - 1; ++it)
    g256_iter(Ag, Bg, lda, ldb, As, Bs, acc, it << 7, false);
  g256_iter(Ag, Bg, lda, ldb, As, Bs, acc, (NIT - 1) << 7, true);
}

// ---------------------------------------------------------------------------
// gemm128_k64 (BK=64 dbuf, 256 thr): unchanged R11 structure for scores/pv.
// ---------------------------------------------------------------------------
__device__ __forceinline__ void gemm128_k64(
    const unsigned short* __restrict__ Ag, const unsigned short* __restrict__ Bg,
    int lda, int ldb, int nk, unsigned short* As, unsigned short* Bs,
    f32x4 acc[4][4]) {
  const int tid = threadIdx.x;
  const int lane = tid & 63, wave = tid >> 6;
  const int wm = wave >> 1, wn = wave & 1;
  const int sr = lane >> 3;                     // staging row within 8-row chunk
  const int scb = ((lane & 7) ^ sr) * 8;        // swizzled source col (ush)
  const int rr = lane & 15, qq = lane >> 4;
  const int slot0 = ((qq) ^ (rr & 7)) * 8;      // k-half 0 read col
  const int slot1 = ((4 + qq) ^ (rr & 7)) * 8;  // k-half 1 read col

#pragma unroll
  for (int i = 0; i < 4; ++i)
#pragma unroll
    for (int j = 0; j < 4; ++j) {
      f32x4 z = {0.f, 0.f, 0.f, 0.f};
      acc[i][j] = z;
    }

  // prologue: stage k=0 into buf 0 (16 chunks of 8 rows; wave w: 4w..4w+3)
#pragma unroll
  for (int c = 0; c < 4; ++c) {
    int chunk = wave * 4 + c;
    int row = chunk * 8 + sr;
    lds_dma16(Ag + (size_t)row * lda + scb, As + chunk * 512);
    lds_dma16(Bg + (size_t)row * ldb + scb, Bs + chunk * 512);
  }

  int buf = 0;
  for (int k0 = 0; k0 < nk; k0 += 64) {
    __syncthreads();  // drains staging issued one compute-phase ago
    const int kn = k0 + 64;
    if (kn < nk) {
      unsigned short* An = As + (buf ^ 1) * 8192;
      unsigned short* Bn = Bs + (buf ^ 1) * 8192;
#pragma unroll
      for (int c = 0; c < 4; ++c) {
        int chunk = wave * 4 + c;
        int row = chunk * 8 + sr;
        lds_dma16(Ag + (size_t)row * lda + kn + scb, An + chunk * 512);
        lds_dma16(Bg + (size_t)row * ldb + kn + scb, Bn + chunk * 512);
      }
    }

    const unsigned short* Ar = As + buf * 8192 + (wm * 64 + rr) * 64;
    const unsigned short* Br = Bs + buf * 8192 + (wn * 64 + rr) * 64;
    {
      f16x8 af[4], bf[4];
#pragma unroll
      for (int i = 0; i < 4; ++i) af[i] = *(const f16x8*)(Ar + i * 1024 + slot0);
#pragma unroll
      for (int j = 0; j < 4; ++j) bf[j] = *(const f16x8*)(Br + j * 1024 + slot0);
#pragma unroll
      for (int i = 0; i < 4; ++i)
#pragma unroll
        for (int j = 0; j < 4; ++j)
          acc[i][j] = __builtin_amdgcn_mfma_f32_16x16x32_f16(af[i], bf[j],
                                                             acc[i][j], 0, 0, 0);
    }
    {
      f16x8 af[4], bf[4];
#pragma unroll
      for (int i = 0; i < 4; ++i) af[i] = *(const f16x8*)(Ar + i * 1024 + slot1);
#pragma unroll
      for (int j = 0; j < 4; ++j) bf[j] = *(const f16x8*)(Br + j * 1024 + slot1);
#pragma unroll
      for (int i = 0; i < 4; ++i)
#pragma unroll
        for (int j = 0; j < 4; ++j)
          acc[i][j] = __builtin_amdgcn_mfma_f32_16x16x32_f16(af[i], bf[j],
                                                             acc[i][j], 0, 0, 0);
    }
    buf ^= 1;
  }
}

// ---------------------------------------------------------------------------
// fp32 -> f16 convert: x then Wk,Wq,Wv into contiguous [xh | wh];
// last 8 blocks zero rsum (8192 floats).
// ---------------------------------------------------------------------------
__global__ void cvt_kernel(const float* __restrict__ x,
                           const float* __restrict__ w0,
                           const float* __restrict__ w1,
                           const float* __restrict__ w2,
                           unsigned short* __restrict__ dst,
                           float* __restrict__ rsum) {
  int i = blockIdx.x * 256 + threadIdx.x;
  if (i >= 2883584) {
    int z2 = i - 2883584;
    float4 z = {0.f, 0.f, 0.f, 0.f};
    ((float4*)rsum)[z2] = z;
    return;
  }
  const float* s;
  size_t si;
  if (i < 2097152) {
    s = x; si = i;
  } else {
    int j = i - 2097152;
    int z = j >> 18;
    s = (z == 0) ? w0 : ((z == 1) ? w1 : w2);
    si = j & 262143;
  }
  float4 f = ((const float4*)s)[si];
  ushort4 u;
  u.x = f2h(f.x); u.y = f2h(f.y); u.z = f2h(f.z); u.w = f2h(f.w);
  ((ushort4*)dst)[i] = u;
}

// ---------------------------------------------------------------------------
// QKV projection, 256x256 8-phase. 384 jobs, XCD-swizzled (384 = 8*48):
//   job <  256: KQ. tm=job>>3 (token tile), tn=job&7 over [Wk;Wq] (2048 rows)
//               -> kh (tn<4) or qh (tn>=4), + bias per col.
//   job >= 256: V.  dt=(job-256)>>5 (d tile), tt=(job-256)&31 (token tile)
//               C[d,t] = Wv[d-tile] . xh[t-slab]^T -> vT[b][d][t] + bv per row.
// ---------------------------------------------------------------------------
__global__ __launch_bounds__(512, 2) void qkv256_kernel(
    const unsigned short* __restrict__ xh, const unsigned short* __restrict__ wh,
    const float* __restrict__ bk, const float* __restrict__ bq,
    const float* __restrict__ bv, unsigned short* __restrict__ kh,
    unsigned short* __restrict__ qh, unsigned short* __restrict__ vT) {
  __shared__ unsigned short As[32768], Bs[32768];  // 128 KiB total
  const int job = (blockIdx.x & 7) * 48 + (blockIdx.x >> 3);

  const unsigned short* Ag;
  const unsigned short* Bg;
  if (job < 256) {
    const int tm = job >> 3, tn = job & 7;
    Ag = xh + (size_t)tm * 256 * 1024;
    Bg = wh + (size_t)tn * 256 * 1024;
  } else {
    const int j = job - 256;
    const int dt = j >> 5, tt = j & 31;
    Ag = wh + 2097152 + (size_t)dt * 256 * 1024;
    Bg = xh + (size_t)tt * 256 * 1024;
  }

  f32x4 acc[2][2][2][4];
  gemm256(Ag, Bg, 1024, 1024, 1024, As, Bs, acc);

  const int tid = threadIdx.x;
  const int lane = tid & 63, wave = tid >> 6;
  const int qwm = wave >> 1, qwn = wave & 1, rr = lane & 15, qq = lane >> 4;

  if (job < 256) {
    const int tm = job >> 3, tn = job & 7;
    const bool isq = tn >= 4;
    unsigned short* dst = isq ? qh : kh;
    const float* bias = isq ? bq : bk;
    const int nbase = (tn & 3) * 256;
    float bj[2][4];
#pragma unroll
    for (int qn = 0; qn < 2; ++qn)
#pragma unroll
      for (int fj = 0; fj < 4; ++fj)
        bj[qn][fj] = bias[nbase + qn * 128 + qwn * 64 + fj * 16 + rr];
#pragma unroll
    for (int qm = 0; qm < 2; ++qm)
#pragma unroll
      for (int fi = 0; fi < 2; ++fi)
#pragma unroll
        for (int reg = 0; reg < 4; ++reg) {
          const int m = tm * 256 + qm * 128 + qwm * 32 + fi * 16 + qq * 4 + reg;
#pragma unroll
          for (int qn = 0; qn < 2; ++qn)
#pragma unroll
            for (int fj = 0; fj < 4; ++fj) {
              const int n = nbase + qn * 128 + qwn * 64 + fj * 16 + rr;
              dst[(size_t)m * 1024 + n] =
                  f2h(acc[qm][qn][fi][fj][reg] + bj[qn][fj]);
            }
        }
  } else {
    const int j = job - 256;
    const int dt = j >> 5, tt = j & 31;
#pragma unroll
    for (int qm = 0; qm < 2; ++qm)
#pragma unroll
      for (int fi = 0; fi < 2; ++fi) {
        const int d0 = dt * 256 + qm * 128 + qwm * 32 + fi * 16 + qq * 4;
        const float4 b4 = *(const float4*)(bv + d0);
        const float bir[4] = {b4.x, b4.y, b4.z, b4.w};
#pragma unroll
        for (int reg = 0; reg < 4; ++reg) {
          const int d = d0 + reg;
#pragma unroll
          for (int qn = 0; qn < 2; ++qn)
#pragma unroll
            for (int fj = 0; fj < 4; ++fj) {
              const int tg = tt * 256 + qn * 128 + qwn * 64 + fj * 16 + rr;
              const int bb = tg >> 11, t = tg & 2047;
              vT[((size_t)(bb * 1024 + d)) * 2048 + t] =
                  f2h(acc[qm][qn][fi][fj][reg] + bir[reg]);
            }
        }
      }
  }
}

// ---------------------------------------------------------------------------
// scores: P[b,s,t] = exp(k[s].q[t]/32 - 4) for t<=s else 0  (f16), plus
// fused row-sum atomics. Triangular grid (136,4). BK=64 dbuf pipeline.
// ---------------------------------------------------------------------------
__global__ __launch_bounds__(256) void scores_kernel(
    const unsigned short* __restrict__ kh, const unsigned short* __restrict__ qh,
    unsigned short* __restrict__ P, float* __restrict__ rsum) {
  const int b = blockIdx.y;
  int idx = blockIdx.x;
  int ts = (int)((sqrtf(8.0f * idx + 1.0f) - 1.0f) * 0.5f);
  while ((ts + 1) * (ts + 2) / 2 <= idx) ++ts;
  while (ts * (ts + 1) / 2 > idx) --ts;
  const int tt = idx - ts * (ts + 1) / 2;
  __shared__ unsigned short As[2 * 128 * 64], Bs[2 * 128 * 64];

  f32x4 acc[4][4];
  gemm128_k64(kh + ((size_t)(b * 2048 + ts * 128)) * 1024,
              qh + ((size_t)(b * 2048 + tt * 128)) * 1024,
              1024, 1024, 1024, As, Bs, acc);

  const int lane = threadIdx.x & 63, wave = threadIdx.x >> 6;
  const int wm = wave >> 1, wn = wave & 1, rr = lane & 15, qq = lane >> 4;
  unsigned short* Pb = P + (size_t)b * 2048 * 2048;
  float* rs = rsum + b * 2048;
#pragma unroll
  for (int i = 0; i < 4; ++i)
#pragma unroll
    for (int reg = 0; reg < 4; ++reg) {
      int srow = ts * 128 + wm * 64 + i * 16 + qq * 4 + reg;
      float p = 0.f;
#pragma unroll
      for (int j = 0; j < 4; ++j) {
        int tcol = tt * 128 + wn * 64 + j * 16 + rr;
        float e = (tcol <= srow) ? __expf(acc[i][j][reg] * 0.03125f - 4.0f)
                                 : 0.0f;
        Pb[(size_t)srow * 2048 + tcol] = f2h(e);
        p += e;
      }
#pragma unroll
      for (int off = 1; off < 16; off <<= 1) p += __shfl_xor(p, off);
      if (rr == 0) atomicAdd(rs + srow, p);
    }
}

// ---------------------------------------------------------------------------
// pv: out[b,s,d] = (1/rsum[b,s]) * sum_t P[b,s,t] * vT[b,d,t]   (fp32 out)
// grid (8,16,4); K truncated to (ts+1)*128; y reversed (big-K first).
// BK=64 dbuf pipeline.
// ---------------------------------------------------------------------------
__global__ __launch_bounds__(256) void pv_gemm_kernel(
    const unsigned short* __restrict__ P, const unsigned short* __restrict__ vT,
    const float* __restrict__ rsum, float* __restrict__ out) {
  const int td = blockIdx.x, ts = 15 - blockIdx.y, b = blockIdx.z;
  __shared__ unsigned short As[2 * 128 * 64], Bs[2 * 128 * 64];

  f32x4 acc[4][4];
  gemm128_k64(P + ((size_t)(b * 2048 + ts * 128)) * 2048,
              vT + ((size_t)(b * 1024 + td * 128)) * 2048,
              2048, 2048, (ts + 1) * 128, As, Bs, acc);

  const int lane = threadIdx.x & 63, wave = threadIdx.x >> 6;
  const int wm = wave >> 1, wn = wave & 1, rr = lane & 15, qq = lane >> 4;
#pragma unroll
  for (int i = 0; i < 4; ++i) {
    int s0 = ts * 128 + wm * 64 + i * 16 + qq * 4;
    float4 r4 = *(const float4*)(rsum + b * 2048 + s0);
    float rv[4] = {__builtin_amdgcn_rcpf(r4.x), __builtin_amdgcn_rcpf(r4.y),
                   __builtin_amdgcn_rcpf(r4.z), __builtin_amdgcn_rcpf(r4.w)};
#pragma unroll
    for (int reg = 0; reg < 4; ++reg) {
      int srow = s0 + reg;
#pragma unroll
      for (int j = 0; j < 4; ++j) {
        int dcol = td * 128 + wn * 64 + j * 16 + rr;
        out[((size_t)(b * 2048 + srow)) * 1024 + dcol] =
            acc[i][j][reg] * rv[reg];
      }
    }
  }
}

// ---------------------------------------------------------------------------
// launch
// ---------------------------------------------------------------------------
extern "C" void kernel_launch(void* const* d_in, const int* in_sizes, int n_in,
                              void* d_out, int out_size, void* d_ws,
                              size_t ws_size, hipStream_t stream) {
  const float* x  = (const float*)d_in[0];
  const float* Wk = (const float*)d_in[1];
  const float* bk = (const float*)d_in[2];
  const float* Wq = (const float*)d_in[3];
  const float* bq = (const float*)d_in[4];
  const float* Wv = (const float*)d_in[5];
  const float* bv = (const float*)d_in[6];
  float* out = (float*)d_out;

  char* ws = (char*)d_ws;
  const size_t MB = 1ull << 20;
  // Aliased layout (86 MB + 32 KB): P overlays xh/wh (dead by scores).
  unsigned short* xh = (unsigned short*)(ws + 0);        // 16 MB  [0,16)
  unsigned short* wh = (unsigned short*)(ws + 16 * MB);  //  6 MB  [16,22)
  unsigned short* P  = (unsigned short*)(ws + 0);        // 32 MB  [0,32) alias
  unsigned short* kh = (unsigned short*)(ws + 38 * MB);  // 16 MB  [38,54)
  unsigned short* qh = (unsigned short*)(ws + 54 * MB);  // 16 MB  [54,70)
  unsigned short* vT = (unsigned short*)(ws + 70 * MB);  // 16 MB  [70,86)
  float* rsum = (float*)(ws + 86 * MB);                  // 32 KB

  // 1) converts (x + 3 W) + rsum zero-init (last 8 blocks)
  cvt_kernel<<<11272, 256, 0, stream>>>(x, Wk, Wq, Wv, xh, rsum);
  // 2) QKV projections, 256^2 8-phase; V operand-swapped -> writes vT directly
  qkv256_kernel<<<384, 512, 0, stream>>>(xh, wh, bk, bq, bv, kh, qh, vT);
  // 3) masked exp(scores) + fused row-sum atomics (BK=64 dbuf)
  scores_kernel<<<dim3(136, 4), 256, 0, stream>>>(kh, qh, P, rsum);
  // 4) (P @ v) * (1/rsum) -> out (BK=64 dbuf)
  pv_gemm_kernel<<<dim3(8, 16, 4), 256, 0, stream>>>(P, vT, rsum, out);
}

// Round 2
// 244.478 us; speedup vs baseline: 1.0010x; 1.0010x over previous
//
#include <hip/hip_runtime.h>
#include <cstdint>

// ---------------------------------------------------------------------------
// DefaultAttention: x[4,2048,1024] fp32; k=xWk^T+bk, q=xWq^T+bq, v=xWv^T+bv;
// sim = k q^T / 32 (causal tril), attn = softmax(sim), out = attn @ v (fp32).
// R13: qkv gemm256 rebuilt with m201 wave geometry (2M x 4N waves, 128x64
// per-wave tile). R12's quadrant walk issued 48 ds_read_b128 per wave per
// K-64 for 64 MFMA (LDS-read-bound, MfmaUtil 25%); this walk needs 24
// (8 A-frags + 4 B-frags per 32-MFMA phase) and halves the barrier count
// (8 per K-128). Staging: P0/P1 stage buf1(cur), P2/P3 stage buf0(next);
// vmcnt(0) at P1/P3 ends -- every waited load is >=1 full 32-MFMA phase old
// (~1400cy), so the drain is hidden, unlike a same-phase drain.
// Liveness (verified): b0 read P0,P1; b1 read P2,P3. b1(n) staged P0,P1(n)
// (region free after P3(n-1) barrier; landed via P1-end vmcnt(0)+barrier).
// b0(n+1) staged P2,P3(n) (free after P1(n)); landed via P3-end vmcnt(0).
// scores/pv keep the R11 BK=64 dbuf structure (unchanged this round).
// ---------------------------------------------------------------------------

typedef __attribute__((ext_vector_type(8))) _Float16 f16x8;
typedef __attribute__((ext_vector_type(4))) float f32x4;

__device__ __forceinline__ unsigned short f2h(float x) {
  return __builtin_bit_cast(unsigned short, (_Float16)x);
}

// async global->LDS, 16B per lane; LDS dest = wave-uniform base + lane*16
__device__ __forceinline__ void lds_dma16(const void* g, void* l) {
  auto gp = reinterpret_cast<const __attribute__((address_space(1))) void*>(
      reinterpret_cast<uintptr_t>(g));
  auto lp = reinterpret_cast<__attribute__((address_space(3))) void*>(
      reinterpret_cast<uintptr_t>(l));
  __builtin_amdgcn_global_load_lds(gp, lp, 16, 0, 0);
}

// ---------------------------------------------------------------------------
// stage_half: 128 rows x 64 cols f16 (16 KB) global -> LDS, 512 threads,
// 2 dma/thread. LDS dest linear (DMA rule); swizzle via pre-swizzled global
// source: LDS slot s of row r holds source col-block s^(r&7); readers use
// slot (cb ^ (r&7)).  [R3-verified scheme, 0 bank conflicts measured]
// ---------------------------------------------------------------------------
__device__ __forceinline__ void stage_half(const unsigned short* __restrict__ G,
                                           int ld, unsigned short* lds,
                                           int tid) {
  const int r = tid >> 3;                      // rows 0..63 (dma 0)
  const int c = ((tid & 7) ^ (r & 7)) * 8;     // swizzled source col (ush)
  lds_dma16(G + (size_t)r * ld + c, lds + tid * 8);
  lds_dma16(G + (size_t)(r + 64) * ld + c, lds + 4096 + tid * 8);  // rows 64..127
}

// ---------------------------------------------------------------------------
// gemm256: C[256x256] = A[256 x nk] * B[256 x nk]^T, nk % 128 == 0.
// 8 waves as 2M x 4N; per-wave output 128x64 (acc[8][4]).
// 4 phases per K-128 iteration; phase (b,h) = 32 MFMA, 12 ds_read_b128.
// ---------------------------------------------------------------------------
__device__ __forceinline__ void gemm256(
    const unsigned short* __restrict__ Ag, const unsigned short* __restrict__ Bg,
    int lda, int ldb, int nk, unsigned short* As, unsigned short* Bs,
    f32x4 (&acc)[8][4]) {
  const int tid = threadIdx.x;
  const int lane = tid & 63, wave = tid >> 6;
  const int wr = wave >> 2, wc = wave & 3;     // 2M x 4N wave grid
  const int rr = lane & 15, qq = lane >> 4;
  const int s7 = rr & 7;
  const int soff0 = (qq ^ s7) * 8;             // k-half 0 swizzled slot
  const int soff1 = ((4 + qq) ^ s7) * 8;       // k-half 1
  const int aoff = wr * 8192 + rr * 64;        // A: row-half wr, row rr+fi*16
  const int boff = (wc >> 1) * 8192 + (wc & 1) * 4096 + rr * 64;

#pragma unroll
  for (int fi = 0; fi < 8; ++fi)
#pragma unroll
    for (int fj = 0; fj < 4; ++fj) {
      f32x4 z = {0.f, 0.f, 0.f, 0.f};
      acc[fi][fj] = z;
    }

  // prologue: stage b0 (cols 0..63, 4 halves); cold-latency drain once.
  stage_half(Ag, lda, As, tid);
  stage_half(Ag + (size_t)128 * lda, lda, As + 8192, tid);
  stage_half(Bg, ldb, Bs, tid);
  stage_half(Bg + (size_t)128 * ldb, ldb, Bs + 8192, tid);
  asm volatile("s_waitcnt vmcnt(0)" ::: "memory");
  __builtin_amdgcn_s_barrier();

  for (int k0 = 0; k0 < nk; k0 += 128) {
    const bool last = (k0 + 128 >= nk);
#pragma unroll
    for (int P = 0; P < 4; ++P) {
      const int b = P >> 1;
      // --- staging (one operand, 2 halves = 4 dma/thread per phase) ---
      if (P == 0) {          // b1(cur) A  <- cols k0+64
        stage_half(Ag + (k0 + 64), lda, As + 16384, tid);
        stage_half(Ag + (size_t)128 * lda + (k0 + 64), lda, As + 24576, tid);
      } else if (P == 1) {   // b1(cur) B
        stage_half(Bg + (k0 + 64), ldb, Bs + 16384, tid);
        stage_half(Bg + (size_t)128 * ldb + (k0 + 64), ldb, Bs + 24576, tid);
      } else if (!last) {
        if (P == 2) {        // b0(next) A <- cols k0+128
          stage_half(Ag + (k0 + 128), lda, As, tid);
          stage_half(Ag + (size_t)128 * lda + (k0 + 128), lda, As + 8192, tid);
        } else {             // b0(next) B
          stage_half(Bg + (k0 + 128), ldb, Bs, tid);
          stage_half(Bg + (size_t)128 * ldb + (k0 + 128), ldb, Bs + 8192, tid);
        }
      }
      // --- register subtile: 8 A-frags + 4 B-frags ---
      const int so = (P & 1) ? soff1 : soff0;
      const unsigned short* Ar = As + b * 16384 + aoff + so;
      const unsigned short* Br = Bs + b * 16384 + boff + so;
      f16x8 af[8], bf[4];
#pragma unroll
      for (int fi = 0; fi < 8; ++fi) af[fi] = *(const f16x8*)(Ar + fi * 1024);
#pragma unroll
      for (int fj = 0; fj < 4; ++fj) bf[fj] = *(const f16x8*)(Br + fj * 1024);
      asm volatile("s_waitcnt lgkmcnt(8)" ::: "memory");
      __builtin_amdgcn_s_barrier();
      asm volatile("s_waitcnt lgkmcnt(0)" ::: "memory");
      __builtin_amdgcn_sched_barrier(0);
      __builtin_amdgcn_s_setprio(1);
#pragma unroll
      for (int fi = 0; fi < 8; ++fi)
#pragma unroll
        for (int fj = 0; fj < 4; ++fj)
          acc[fi][fj] = __builtin_amdgcn_mfma_f32_16x16x32_f16(
              af[fi], bf[fj], acc[fi][fj], 0, 0, 0);
      __builtin_amdgcn_s_setprio(0);
      // drains: waited loads are >=1 full 32-MFMA phase old (hidden)
      if (P == 1) {
        asm volatile("s_waitcnt vmcnt(0)" ::: "memory");
      } else if (P == 3 && !last) {
        asm volatile("s_waitcnt vmcnt(0)" ::: "memory");
      }
      __builtin_amdgcn_s_barrier();
    }
  }
}

// ---------------------------------------------------------------------------
// gemm128_k64 (BK=64 dbuf, 256 thr): unchanged R11 structure for scores/pv.
// ---------------------------------------------------------------------------
__device__ __forceinline__ void gemm128_k64(
    const unsigned short* __restrict__ Ag, const unsigned short* __restrict__ Bg,
    int lda, int ldb, int nk, unsigned short* As, unsigned short* Bs,
    f32x4 acc[4][4]) {
  const int tid = threadIdx.x;
  const int lane = tid & 63, wave = tid >> 6;
  const int wm = wave >> 1, wn = wave & 1;
  const int sr = lane >> 3;                     // staging row within 8-row chunk
  const int scb = ((lane & 7) ^ sr) * 8;        // swizzled source col (ush)
  const int rr = lane & 15, qq = lane >> 4;
  const int slot0 = ((qq) ^ (rr & 7)) * 8;      // k-half 0 read col
  const int slot1 = ((4 + qq) ^ (rr & 7)) * 8;  // k-half 1 read col

#pragma unroll
  for (int i = 0; i < 4; ++i)
#pragma unroll
    for (int j = 0; j < 4; ++j) {
      f32x4 z = {0.f, 0.f, 0.f, 0.f};
      acc[i][j] = z;
    }

  // prologue: stage k=0 into buf 0 (16 chunks of 8 rows; wave w: 4w..4w+3)
#pragma unroll
  for (int c = 0; c < 4; ++c) {
    int chunk = wave * 4 + c;
    int row = chunk * 8 + sr;
    lds_dma16(Ag + (size_t)row * lda + scb, As + chunk * 512);
    lds_dma16(Bg + (size_t)row * ldb + scb, Bs + chunk * 512);
  }

  int buf = 0;
  for (int k0 = 0; k0 < nk; k0 += 64) {
    __syncthreads();  // drains staging issued one compute-phase ago
    const int kn = k0 + 64;
    if (kn < nk) {
      unsigned short* An = As + (buf ^ 1) * 8192;
      unsigned short* Bn = Bs + (buf ^ 1) * 8192;
#pragma unroll
      for (int c = 0; c < 4; ++c) {
        int chunk = wave * 4 + c;
        int row = chunk * 8 + sr;
        lds_dma16(Ag + (size_t)row * lda + kn + scb, An + chunk * 512);
        lds_dma16(Bg + (size_t)row * ldb + kn + scb, Bn + chunk * 512);
      }
    }

    const unsigned short* Ar = As + buf * 8192 + (wm * 64 + rr) * 64;
    const unsigned short* Br = Bs + buf * 8192 + (wn * 64 + rr) * 64;
    {
      f16x8 af[4], bf[4];
#pragma unroll
      for (int i = 0; i < 4; ++i) af[i] = *(const f16x8*)(Ar + i * 1024 + slot0);
#pragma unroll
      for (int j = 0; j < 4; ++j) bf[j] = *(const f16x8*)(Br + j * 1024 + slot0);
#pragma unroll
      for (int i = 0; i < 4; ++i)
#pragma unroll
        for (int j = 0; j < 4; ++j)
          acc[i][j] = __builtin_amdgcn_mfma_f32_16x16x32_f16(af[i], bf[j],
                                                             acc[i][j], 0, 0, 0);
    }
    {
      f16x8 af[4], bf[4];
#pragma unroll
      for (int i = 0; i < 4; ++i) af[i] = *(const f16x8*)(Ar + i * 1024 + slot1);
#pragma unroll
      for (int j = 0; j < 4; ++j) bf[j] = *(const f16x8*)(Br + j * 1024 + slot1);
#pragma unroll
      for (int i = 0; i < 4; ++i)
#pragma unroll
        for (int j = 0; j < 4; ++j)
          acc[i][j] = __builtin_amdgcn_mfma_f32_16x16x32_f16(af[i], bf[j],
                                                             acc[i][j], 0, 0, 0);
    }
    buf ^= 1;
  }
}

// ---------------------------------------------------------------------------
// fp32 -> f16 convert: x then Wk,Wq,Wv into contiguous [xh | wh];
// last 8 blocks zero rsum (8192 floats).
// ---------------------------------------------------------------------------
__global__ void cvt_kernel(const float* __restrict__ x,
                           const float* __restrict__ w0,
                           const float* __restrict__ w1,
                           const float* __restrict__ w2,
                           unsigned short* __restrict__ dst,
                           float* __restrict__ rsum) {
  int i = blockIdx.x * 256 + threadIdx.x;
  if (i >= 2883584) {
    int z2 = i - 2883584;
    float4 z = {0.f, 0.f, 0.f, 0.f};
    ((float4*)rsum)[z2] = z;
    return;
  }
  const float* s;
  size_t si;
  if (i < 2097152) {
    s = x; si = i;
  } else {
    int j = i - 2097152;
    int z = j >> 18;
    s = (z == 0) ? w0 : ((z == 1) ? w1 : w2);
    si = j & 262143;
  }
  float4 f = ((const float4*)s)[si];
  ushort4 u;
  u.x = f2h(f.x); u.y = f2h(f.y); u.z = f2h(f.z); u.w = f2h(f.w);
  ((ushort4*)dst)[i] = u;
}

// ---------------------------------------------------------------------------
// QKV projection, 256x256 4-phase. 384 jobs, XCD-swizzled (384 = 8*48):
//   job <  256: KQ. tm=job>>3 (token tile), tn=job&7 over [Wk;Wq] (2048 rows)
//               -> kh (tn<4) or qh (tn>=4), + bias per col.
//   job >= 256: V.  dt=(job-256)>>5 (d tile), tt=(job-256)&31 (token tile)
//               C[d,t] = Wv[d-tile] . xh[t-slab]^T -> vT[b][d][t] + bv per row.
// ---------------------------------------------------------------------------
__global__ __launch_bounds__(512, 2) void qkv256_kernel(
    const unsigned short* __restrict__ xh, const unsigned short* __restrict__ wh,
    const float* __restrict__ bk, const float* __restrict__ bq,
    const float* __restrict__ bv, unsigned short* __restrict__ kh,
    unsigned short* __restrict__ qh, unsigned short* __restrict__ vT) {
  __shared__ unsigned short As[32768], Bs[32768];  // 128 KiB total
  const int job = (blockIdx.x & 7) * 48 + (blockIdx.x >> 3);

  const unsigned short* Ag;
  const unsigned short* Bg;
  if (job < 256) {
    const int tm = job >> 3, tn = job & 7;
    Ag = xh + (size_t)tm * 256 * 1024;
    Bg = wh + (size_t)tn * 256 * 1024;
  } else {
    const int j = job - 256;
    const int dt = j >> 5, tt = j & 31;
    Ag = wh + 2097152 + (size_t)dt * 256 * 1024;
    Bg = xh + (size_t)tt * 256 * 1024;
  }

  f32x4 acc[8][4];
  gemm256(Ag, Bg, 1024, 1024, 1024, As, Bs, acc);

  const int tid = threadIdx.x;
  const int lane = tid & 63, wave = tid >> 6;
  const int wr = wave >> 2, wc = wave & 3, rr = lane & 15, qq = lane >> 4;

  if (job < 256) {
    const int tm = job >> 3, tn = job & 7;
    const bool isq = tn >= 4;
    unsigned short* dst = isq ? qh : kh;
    const float* bias = isq ? bq : bk;
    const int nbase = (tn & 3) * 256;
    float bj[4];
#pragma unroll
    for (int fj = 0; fj < 4; ++fj)
      bj[fj] = bias[nbase + wc * 64 + fj * 16 + rr];
#pragma unroll
    for (int fi = 0; fi < 8; ++fi)
#pragma unroll
      for (int reg = 0; reg < 4; ++reg) {
        const int m = tm * 256 + wr * 128 + fi * 16 + qq * 4 + reg;
#pragma unroll
        for (int fj = 0; fj < 4; ++fj) {
          const int n = nbase + wc * 64 + fj * 16 + rr;
          dst[(size_t)m * 1024 + n] = f2h(acc[fi][fj][reg] + bj[fj]);
        }
      }
  } else {
    const int j = job - 256;
    const int dt = j >> 5, tt = j & 31;
#pragma unroll
    for (int fi = 0; fi < 8; ++fi) {
      const int d0 = dt * 256 + wr * 128 + fi * 16 + qq * 4;
      const float4 b4 = *(const float4*)(bv + d0);
      const float bir[4] = {b4.x, b4.y, b4.z, b4.w};
#pragma unroll
      for (int reg = 0; reg < 4; ++reg) {
        const int d = d0 + reg;
#pragma unroll
        for (int fj = 0; fj < 4; ++fj) {
          const int tg = tt * 256 + wc * 64 + fj * 16 + rr;
          const int bb = tg >> 11, t = tg & 2047;
          vT[((size_t)(bb * 1024 + d)) * 2048 + t] =
              f2h(acc[fi][fj][reg] + bir[reg]);
        }
      }
    }
  }
}

// ---------------------------------------------------------------------------
// scores: P[b,s,t] = exp(k[s].q[t]/32 - 4) for t<=s else 0  (f16), plus
// fused row-sum atomics. Triangular grid (136,4). BK=64 dbuf pipeline.
// ---------------------------------------------------------------------------
__global__ __launch_bounds__(256) void scores_kernel(
    const unsigned short* __restrict__ kh, const unsigned short* __restrict__ qh,
    unsigned short* __restrict__ P, float* __restrict__ rsum) {
  const int b = blockIdx.y;
  int idx = blockIdx.x;
  int ts = (int)((sqrtf(8.0f * idx + 1.0f) - 1.0f) * 0.5f);
  while ((ts + 1) * (ts + 2) / 2 <= idx) ++ts;
  while (ts * (ts + 1) / 2 > idx) --ts;
  const int tt = idx - ts * (ts + 1) / 2;
  __shared__ unsigned short As[2 * 128 * 64], Bs[2 * 128 * 64];

  f32x4 acc[4][4];
  gemm128_k64(kh + ((size_t)(b * 2048 + ts * 128)) * 1024,
              qh + ((size_t)(b * 2048 + tt * 128)) * 1024,
              1024, 1024, 1024, As, Bs, acc);

  const int lane = threadIdx.x & 63, wave = threadIdx.x >> 6;
  const int wm = wave >> 1, wn = wave & 1, rr = lane & 15, qq = lane >> 4;
  unsigned short* Pb = P + (size_t)b * 2048 * 2048;
  float* rs = rsum + b * 2048;
#pragma unroll
  for (int i = 0; i < 4; ++i)
#pragma unroll
    for (int reg = 0; reg < 4; ++reg) {
      int srow = ts * 128 + wm * 64 + i * 16 + qq * 4 + reg;
      float p = 0.f;
#pragma unroll
      for (int j = 0; j < 4; ++j) {
        int tcol = tt * 128 + wn * 64 + j * 16 + rr;
        float e = (tcol <= srow) ? __expf(acc[i][j][reg] * 0.03125f - 4.0f)
                                 : 0.0f;
        Pb[(size_t)srow * 2048 + tcol] = f2h(e);
        p += e;
      }
#pragma unroll
      for (int off = 1; off < 16; off <<= 1) p += __shfl_xor(p, off);
      if (rr == 0) atomicAdd(rs + srow, p);
    }
}

// ---------------------------------------------------------------------------
// pv: out[b,s,d] = (1/rsum[b,s]) * sum_t P[b,s,t] * vT[b,d,t]   (fp32 out)
// grid (8,16,4); K truncated to (ts+1)*128; y reversed (big-K first).
// BK=64 dbuf pipeline.
// ---------------------------------------------------------------------------
__global__ __launch_bounds__(256) void pv_gemm_kernel(
    const unsigned short* __restrict__ P, const unsigned short* __restrict__ vT,
    const float* __restrict__ rsum, float* __restrict__ out) {
  const int td = blockIdx.x, ts = 15 - blockIdx.y, b = blockIdx.z;
  __shared__ unsigned short As[2 * 128 * 64], Bs[2 * 128 * 64];

  f32x4 acc[4][4];
  gemm128_k64(P + ((size_t)(b * 2048 + ts * 128)) * 2048,
              vT + ((size_t)(b * 1024 + td * 128)) * 2048,
              2048, 2048, (ts + 1) * 128, As, Bs, acc);

  const int lane = threadIdx.x & 63, wave = threadIdx.x >> 6;
  const int wm = wave >> 1, wn = wave & 1, rr = lane & 15, qq = lane >> 4;
#pragma unroll
  for (int i = 0; i < 4; ++i) {
    int s0 = ts * 128 + wm * 64 + i * 16 + qq * 4;
    float4 r4 = *(const float4*)(rsum + b * 2048 + s0);
    float rv[4] = {__builtin_amdgcn_rcpf(r4.x), __builtin_amdgcn_rcpf(r4.y),
                   __builtin_amdgcn_rcpf(r4.z), __builtin_amdgcn_rcpf(r4.w)};
#pragma unroll
    for (int reg = 0; reg < 4; ++reg) {
      int srow = s0 + reg;
#pragma unroll
      for (int j = 0; j < 4; ++j) {
        int dcol = td * 128 + wn * 64 + j * 16 + rr;
        out[((size_t)(b * 2048 + srow)) * 1024 + dcol] =
            acc[i][j][reg] * rv[reg];
      }
    }
  }
}

// ---------------------------------------------------------------------------
// launch
// ---------------------------------------------------------------------------
extern "C" void kernel_launch(void* const* d_in, const int* in_sizes, int n_in,
                              void* d_out, int out_size, void* d_ws,
                              size_t ws_size, hipStream_t stream) {
  const float* x  = (const float*)d_in[0];
  const float* Wk = (const float*)d_in[1];
  const float* bk = (const float*)d_in[2];
  const float* Wq = (const float*)d_in[3];
  const float* bq = (const float*)d_in[4];
  const float* Wv = (const float*)d_in[5];
  const float* bv = (const float*)d_in[6];
  float* out = (float*)d_out;

  char* ws = (char*)d_ws;
  const size_t MB = 1ull << 20;
  // Aliased layout (86 MB + 32 KB): P overlays xh/wh (dead by scores).
  unsigned short* xh = (unsigned short*)(ws + 0);        // 16 MB  [0,16)
  unsigned short* wh = (unsigned short*)(ws + 16 * MB);  //  6 MB  [16,22)
  unsigned short* P  = (unsigned short*)(ws + 0);        // 32 MB  [0,32) alias
  unsigned short* kh = (unsigned short*)(ws + 38 * MB);  // 16 MB  [38,54)
  unsigned short* qh = (unsigned short*)(ws + 54 * MB);  // 16 MB  [54,70)
  unsigned short* vT = (unsigned short*)(ws + 70 * MB);  // 16 MB  [70,86)
  float* rsum = (float*)(ws + 86 * MB);                  // 32 KB

  // 1) converts (x + 3 W) + rsum zero-init (last 8 blocks)
  cvt_kernel<<<11272, 256, 0, stream>>>(x, Wk, Wq, Wv, xh, rsum);
  // 2) QKV projections, 256^2 4-phase; V operand-swapped -> writes vT directly
  qkv256_kernel<<<384, 512, 0, stream>>>(xh, wh, bk, bq, bv, kh, qh, vT);
  // 3) masked exp(scores) + fused row-sum atomics (BK=64 dbuf)
  scores_kernel<<<dim3(136, 4), 256, 0, stream>>>(kh, qh, P, rsum);
  // 4) (P @ v) * (1/rsum) -> out (BK=64 dbuf)
  pv_gemm_kernel<<<dim3(8, 16, 4), 256, 0, stream>>>(P, vT, rsum, out);
}